// Round 9
// baseline (264.583 us; speedup 1.0000x reference)
//
#include <hip/hip_runtime.h>

#define N_NODES 50000
#define N_EDGES 500000
#define F_IN    128
#define HID     160
#define NG      50
#define OUT_DIM 10
#define PC      16          // padded column count: 10 logits + col10 = ones-carrier
#define MAXDEG  48          // Poisson(10) max over 50k nodes ~ 30; 48 is beyond-safe
#define PADK    164         // transposed stage-buffer stride (>=160, %4==0)
#define FSTRIDE 132         // Fmt row stride (>=128, %4==0)

#define NRANGE  8           // one dst-range per XCD
#define RNODES  (N_NODES / NRANGE)      // 6250
#define FILLB   128         // fill blocks per range (occupancy for the latency-bound fill)
#define FB      (NRANGE * FILLB)        // 1024 fill blocks
#define NPACK   (N_EDGES / 4)           // 125000 int4 packs

#define XF_ROWS   32
#define XF_BLOCKS ((N_NODES + XF_ROWS - 1) / XF_ROWS)    // 1563
#define ZERO_BLOCKS ((N_NODES + 255) / 256)              // 196

// ---- kernel 1: weight chain (block 0) | starts (block 1) | zero deg (blocks 2+) ----
// Chain (transposed stage buffers Bt[c][k], stride PADK):
//   fcwT -> T3t = (W3@fcw)^T -> T2t (r2=b2@T3) -> T1t (r1=b1@T2) -> Fmt (r0=b0@T1); r3=b3@fcw
// Thread-per-row: thread r computes out[r][0..9]; W row read once as float4s;
// B read from LDS at wave-uniform addresses (broadcast, conflict-free).
__global__ void k_init(const float* __restrict__ W0, const float* __restrict__ b0,
                       const float* __restrict__ W1, const float* __restrict__ b1,
                       const float* __restrict__ W2, const float* __restrict__ b2,
                       const float* __restrict__ W3, const float* __restrict__ b3,
                       const float* __restrict__ fcw, const int* __restrict__ batch,
                       float* __restrict__ Fmt, float* __restrict__ r0,
                       float* __restrict__ r1, float* __restrict__ r2,
                       float* __restrict__ r3, int* __restrict__ start,
                       int* __restrict__ deg) {
    const int t = threadIdx.x;
    if (blockIdx.x >= 2) {               // ---- zero deg ----
        int i = (blockIdx.x - 2) * 256 + t;
        if (i < N_NODES) deg[i] = 0;
        return;
    }
    if (blockIdx.x == 1) {               // ---- per-graph starts (batch sorted) ----
        int g = t;
        if (g > NG) return;
        int lo = 0, hi = N_NODES;
        while (lo < hi) {
            int mid = (lo + hi) >> 1;
            if (batch[mid] < g) lo = mid + 1; else hi = mid;
        }
        start[g] = lo;
        return;
    }
    // ---- block 0: weight chain ----
    __shared__ float sA[OUT_DIM * PADK];
    __shared__ float sB[OUT_DIM * PADK];
    float* cur = sA;
    float* nxt = sB;

    // cur <- fcw^T  (fcw is [128 x 10] row-major)
    for (int idx = t; idx < F_IN * OUT_DIM; idx += 256) {
        int k = idx / OUT_DIM, c = idx - k * OUT_DIM;
        cur[c * PADK + k] = fcw[idx];
    }
    __syncthreads();
    if (t < OUT_DIM) {                   // r3 = b3^T fcw
        float acc = 0.f;
        const float4* Bv = (const float4*)b3;
        for (int k4 = 0; k4 < F_IN / 4; ++k4) {
            float4 w = Bv[k4];
            float4 b = *(const float4*)&cur[t * PADK + 4 * k4];
            acc += w.x * b.x + w.y * b.y + w.z * b.z + w.w * b.w;
        }
        r3[t] = acc;
    }
    __syncthreads();

    auto stage = [&](const float* __restrict__ W, const float* __restrict__ bias,
                     float* __restrict__ biasOut, int M, int K, bool toGlobal) {
        const int r = t;
        const bool isBias = (r == M) && (bias != nullptr);
        if (r < M || isBias) {
            const float* Arow = isBias ? bias : (W + r * K);
            const float4* Wv = (const float4*)Arow;
            float acc[OUT_DIM];
            #pragma unroll
            for (int c = 0; c < OUT_DIM; ++c) acc[c] = 0.f;
            #pragma unroll 4
            for (int k4 = 0; k4 < K / 4; ++k4) {
                float4 w = Wv[k4];
                #pragma unroll
                for (int c = 0; c < OUT_DIM; ++c) {
                    float4 b = *(const float4*)&cur[c * PADK + 4 * k4];
                    acc[c] += w.x * b.x + w.y * b.y + w.z * b.z + w.w * b.w;
                }
            }
            if (isBias) {
                #pragma unroll
                for (int c = 0; c < OUT_DIM; ++c) biasOut[c] = acc[c];
            } else if (toGlobal) {
                #pragma unroll
                for (int c = 0; c < OUT_DIM; ++c) Fmt[c * FSTRIDE + r] = acc[c];
            } else {
                #pragma unroll
                for (int c = 0; c < OUT_DIM; ++c) nxt[c * PADK + r] = acc[c];
            }
        }
        __syncthreads();
        float* tmp = cur; cur = nxt; nxt = tmp;
    };

    stage(W3, nullptr, nullptr, HID, F_IN, false);   // T3t = (W3@fcw)^T
    stage(W2, b2, r2, HID, HID, false);              // T2t, r2 = b2@T3
    stage(W1, b1, r1, HID, HID, false);              // T1t, r1 = b1@T2
    stage(W0, b0, r0, F_IN, HID, true);              // Fmt,  r0 = b0@T1
}

// ---- kernel 2: ELL fill XCD-partitioned (blocks < FB) | Y0 = [X@F | ones] (blocks >= FB) ----
// Fill: range r = blockIdx&7 -> nodes [r*6250,(r+1)*6250). Blocks of one residue class land
// on one XCD (round-robin dispatch): ELL rows + deg counters stay in one L2.
// The X@F part streams 25.6 MB of X — co-scheduled with the latency-bound fill (max not sum).
__global__ void k_fill_xf(const int* __restrict__ src, const int* __restrict__ dst,
                          int* __restrict__ deg, int* __restrict__ ell,
                          const float* __restrict__ X, const float* __restrict__ Fmt,
                          float* __restrict__ Y0) {
    const int t = threadIdx.x;
    if (blockIdx.x < FB) {               // ---- ELL fill ----
        const int rb    = blockIdx.x;
        const int range = rb & (NRANGE - 1);
        const int sub   = rb >> 3;                    // 0..FILLB-1
        const int lo    = range * RNODES;
        const int4* d4 = (const int4*)dst;
        const int4* s4 = (const int4*)src;
        for (int pk = sub * 256 + t; pk < NPACK; pk += FILLB * 256) {
            const int4 dv = d4[pk];
            const int4 sv = s4[pk];
            #pragma unroll
            for (int j = 0; j < 4; ++j) {
                const int d = (&dv.x)[j];
                if ((unsigned)(d - lo) < (unsigned)RNODES) {
                    int p = atomicAdd(&deg[d], 1);
                    if (p < MAXDEG) ell[d * MAXDEG + p] = (&sv.x)[j];
                }
            }
        }
        return;
    }
    // ---- X@F part ----
    __shared__ float sX[XF_ROWS][132];   // +4 pad: float4-aligned, conflict-breaking
    __shared__ float sFt[OUT_DIM * FSTRIDE];
    const int base = (blockIdx.x - FB) * XF_ROWS;
    for (int idx = t; idx < XF_ROWS * F_IN; idx += 256) {
        int rr = idx >> 7, kk = idx & 127;
        int gr = base + rr;
        sX[rr][kk] = (gr < N_NODES) ? X[(size_t)gr * F_IN + kk] : 0.f;
    }
    for (int idx = t; idx < OUT_DIM * FSTRIDE; idx += 256) sFt[idx] = Fmt[idx];
    __syncthreads();
    const int r = t >> 4, c = t & 15;
    float a0 = 0.f, a1 = 0.f;
    if (c < OUT_DIM) {
        for (int k = 0; k < F_IN; k += 4) {
            const float4 x0 = *(const float4*)&sX[r][k];
            const float4 x1 = *(const float4*)&sX[r + 16][k];
            const float4 f  = *(const float4*)&sFt[c * FSTRIDE + k];
            a0 += x0.x * f.x + x0.y * f.y + x0.z * f.z + x0.w * f.w;
            a1 += x1.x * f.x + x1.y * f.y + x1.z * f.z + x1.w * f.w;
        }
    }
    const float pad = (c == 10) ? 1.0f : 0.0f;   // col 10 carries the ones vector
    const float v0 = (c < OUT_DIM) ? a0 : pad;
    const float v1 = (c < OUT_DIM) ? a1 : pad;
    const int g0 = base + r, g1 = base + r + 16;
    if (g0 < N_NODES) Y0[(size_t)g0 * PC + c] = v0;
    if (g1 < N_NODES) Y0[(size_t)g1 * PC + c] = v1;
}

// ---------------- propagation: one wave per node; rsqrt computed inline from deg ----------------
__global__ void k_prop16(const float* __restrict__ in, const int* __restrict__ deg,
                         const int* __restrict__ ell, float* __restrict__ out) {
    const int gid  = blockIdx.x * blockDim.x + threadIdx.x;
    const int i    = gid >> 6;                 // node == global wave id (grid exact)
    const int lane = threadIdx.x & 63;
    const int esub = lane >> 4, c = lane & 15;
    const int d = deg[i];
    const int dc = (d < MAXDEG) ? d : MAXDEG;
    float acc = 0.f;
    const int base = i * MAXDEG;
    for (int k = esub; k < dc; k += 4) {
        int s = ell[base + k];
        float ds = rsqrtf((float)deg[s] + 2.0f);
        acc += ds * in[(size_t)s * PC + c];
    }
    acc += __shfl_xor(acc, 16);
    acc += __shfl_xor(acc, 32);
    if (lane < 16) {
        float di = rsqrtf((float)d + 2.0f);
        out[(size_t)i * PC + c] = di * (acc + 2.0f * di * in[(size_t)i * PC + c]);
    }
}

// ---------------- pool + bias terms + fc constant + log_softmax ----------------
__global__ void k_pool_final(const float* __restrict__ Y1, const float* __restrict__ Y2,
                             const float* __restrict__ Y3, const float* __restrict__ Y4,
                             const int* __restrict__ start,
                             const float* __restrict__ r0, const float* __restrict__ r1,
                             const float* __restrict__ r2, const float* __restrict__ r3,
                             const float* __restrict__ fcb, float* __restrict__ out) {
    const int g = blockIdx.x, t = threadIdx.x;  // 256 threads
    __shared__ float red[256];
    __shared__ float S_sh[16];
    __shared__ float qsh[3];
    __shared__ float lg[OUT_DIM];
    const int st = start[g], cnt = start[g + 1] - st;
    const int c = t & 15, rr = t >> 4;

    // S[c] = sum over graph rows of Y4[:, c]
    float acc = 0.f;
    for (int r = rr; r < cnt; r += 16) acc += Y4[(size_t)(st + r) * PC + c];
    red[t] = acc; __syncthreads();
    if (t < 128) red[t] += red[t + 128]; __syncthreads();
    if (t < 64)  red[t] += red[t + 64];  __syncthreads();
    if (t < 32)  red[t] += red[t + 32];  __syncthreads();
    if (t < 16)  S_sh[t] = red[t] + red[t + 16];

    // q1 = sum col10 of Y1, q2 of Y2, q3 of Y3
    float a1 = 0.f, a2 = 0.f, a3 = 0.f;
    for (int r = t; r < cnt; r += 256) {
        a1 += Y1[(size_t)(st + r) * PC + 10];
        a2 += Y2[(size_t)(st + r) * PC + 10];
        a3 += Y3[(size_t)(st + r) * PC + 10];
    }
    __syncthreads(); red[t] = a1; __syncthreads();
    for (int o = 128; o > 0; o >>= 1) { if (t < o) red[t] += red[t + o]; __syncthreads(); }
    if (t == 0) qsh[0] = red[0];
    __syncthreads(); red[t] = a2; __syncthreads();
    for (int o = 128; o > 0; o >>= 1) { if (t < o) red[t] += red[t + o]; __syncthreads(); }
    if (t == 0) qsh[1] = red[0];
    __syncthreads(); red[t] = a3; __syncthreads();
    for (int o = 128; o > 0; o >>= 1) { if (t < o) red[t] += red[t + o]; __syncthreads(); }
    if (t == 0) qsh[2] = red[0];
    __syncthreads();

    if (t < OUT_DIM) {
        float n = (float)cnt; if (n < 1.f) n = 1.f;
        // q3 pairs with r0 = b0^T W1W2W3 fcw; q2 with r1; q1 with r2
        lg[t] = (S_sh[t] + qsh[2] * r0[t] + qsh[1] * r1[t] + qsh[0] * r2[t]) / n
                + r3[t] + fcb[t];
    }
    __syncthreads();
    if (t == 0) {
        float m = -1e30f;
        for (int o = 0; o < OUT_DIM; ++o) m = fmaxf(m, lg[o]);
        float ss = 0.f;
        for (int o = 0; o < OUT_DIM; ++o) ss += expf(lg[o] - m);
        float ls = logf(ss) + m;
        for (int o = 0; o < OUT_DIM; ++o) out[g * OUT_DIM + o] = lg[o] - ls;
    }
}

extern "C" void kernel_launch(void* const* d_in, const int* in_sizes, int n_in,
                              void* d_out, int out_size, void* d_ws, size_t ws_size,
                              hipStream_t stream) {
    const float* x     = (const float*)d_in[0];
    const int*   ei    = (const int*)d_in[1];
    const int*   src   = ei;
    const int*   dstp  = ei + N_EDGES;
    const int*   batch = (const int*)d_in[2];
    const float* W0 = (const float*)d_in[3];
    const float* b0 = (const float*)d_in[4];
    const float* W1 = (const float*)d_in[5];
    const float* b1 = (const float*)d_in[6];
    const float* W2 = (const float*)d_in[7];
    const float* b2 = (const float*)d_in[8];
    const float* W3 = (const float*)d_in[9];
    const float* b3 = (const float*)d_in[10];
    const float* fcw = (const float*)d_in[11];
    const float* fcb = (const float*)d_in[12];
    float* out = (float*)d_out;

    char* p = (char*)d_ws;
    auto alloc = [&](size_t bytes) -> void* {
        void* r = (void*)p;
        p += (bytes + 255) & ~(size_t)255;
        return r;
    };
    int*   deg   = (int*)alloc(N_NODES * 4);
    int*   start = (int*)alloc((NG + 1) * 4);
    int*   ell   = (int*)alloc((size_t)N_NODES * MAXDEG * 4);
    float* Fmt   = (float*)alloc(OUT_DIM * FSTRIDE * 4);
    float* r0    = (float*)alloc(OUT_DIM * 4);
    float* r1    = (float*)alloc(OUT_DIM * 4);
    float* r2    = (float*)alloc(OUT_DIM * 4);
    float* r3    = (float*)alloc(OUT_DIM * 4);
    float* Y0    = (float*)alloc((size_t)N_NODES * PC * 4);
    float* Y1    = (float*)alloc((size_t)N_NODES * PC * 4);
    float* Y2    = (float*)alloc((size_t)N_NODES * PC * 4);
    float* Y3    = (float*)alloc((size_t)N_NODES * PC * 4);
    float* Y4    = (float*)alloc((size_t)N_NODES * PC * 4);

    const int TB = 256;
    // kernel 1: weight chain + starts + zero deg (replaces memset)
    k_init<<<ZERO_BLOCKS + 2, TB, 0, stream>>>(W0, b0, W1, b1, W2, b2, W3, b3,
                                               fcw, batch, Fmt, r0, r1, r2, r3,
                                               start, deg);
    // kernel 2: XCD-partitioned ELL fill + X@F (independent, co-scheduled)
    k_fill_xf<<<FB + XF_BLOCKS, TB, 0, stream>>>(src, dstp, deg, ell, x, Fmt, Y0);

    // 4 propagations of the 16-col matrix (one wave per node, rsqrt inline)
    const int PROP_BLOCKS = N_NODES * 64 / TB;   // 12500
    k_prop16<<<PROP_BLOCKS, TB, 0, stream>>>(Y0, deg, ell, Y1);
    k_prop16<<<PROP_BLOCKS, TB, 0, stream>>>(Y1, deg, ell, Y2);
    k_prop16<<<PROP_BLOCKS, TB, 0, stream>>>(Y2, deg, ell, Y3);
    k_prop16<<<PROP_BLOCKS, TB, 0, stream>>>(Y3, deg, ell, Y4);

    // pool + bias + fc + log_softmax
    k_pool_final<<<NG, TB, 0, stream>>>(Y1, Y2, Y3, Y4, start, r0, r1, r2, r3, fcb, out);
}

// Round 10
// 241.840 us; speedup vs baseline: 1.0940x; 1.0940x over previous
//
#include <hip/hip_runtime.h>

#define N_NODES 50000
#define N_EDGES 500000
#define F_IN    128
#define HID     160
#define NG      50
#define OUT_DIM 10
#define PC      16          // padded column count: 10 logits + col10 = ones-carrier
#define MAXDEG  48          // Poisson(10) max over 50k nodes ~ 30; 48 is beyond-safe
#define PADK    164         // transposed stage-buffer stride (>=160, %4==0)
#define FSTRIDE 132         // Fmt row stride (>=128, %4==0)

#define NRANGE  8           // one dst-range per XCD
#define RNODES  (N_NODES / NRANGE)      // 6250
#define FILLB   128         // fill blocks per range (occupancy for the latency-bound fill)
#define FB      (NRANGE * FILLB)        // 1024 fill blocks
#define NPACK   (N_EDGES / 4)           // 125000 int4 packs

#define XF_ROWS   32
#define XF_BLOCKS ((N_NODES + XF_ROWS - 1) / XF_ROWS)    // 1563
#define ZERO_BLOCKS ((N_NODES + 1023) / 1024)            // 49

// ---- kernel 1: weight chain (block 0) | starts (block 1) | zero deg (blocks 2+) ----
// Chain (transposed stage buffers Bt[c][k], stride PADK):
//   fcwT -> T3t = (W3@fcw)^T -> T2t (r2=b2@T3) -> T1t (r1=b1@T2) -> Fmt (r0=b0@T1); r3=b3@fcw
// Quarter-row threads: 1024-thread block; thread (r = t>>2, q = t&3) loads W[r, q-th
// quarter] as 10 float4s (row-quad reads 64 B contiguous -> coalesced, 4x load ILP of
// thread-per-row); partial dots reduced with shfl_xor(1,2) within the quad.
__global__ __launch_bounds__(1024)
void k_init(const float* __restrict__ W0, const float* __restrict__ b0,
            const float* __restrict__ W1, const float* __restrict__ b1,
            const float* __restrict__ W2, const float* __restrict__ b2,
            const float* __restrict__ W3, const float* __restrict__ b3,
            const float* __restrict__ fcw, const int* __restrict__ batch,
            float* __restrict__ Fmt, float* __restrict__ r0,
            float* __restrict__ r1, float* __restrict__ r2,
            float* __restrict__ r3, int* __restrict__ start,
            int* __restrict__ deg) {
    const int t = threadIdx.x;
    if (blockIdx.x >= 2) {               // ---- zero deg ----
        int i = (blockIdx.x - 2) * 1024 + t;
        if (i < N_NODES) deg[i] = 0;
        return;
    }
    if (blockIdx.x == 1) {               // ---- per-graph starts (batch sorted) ----
        int g = t;
        if (g > NG) return;
        int lo = 0, hi = N_NODES;
        while (lo < hi) {
            int mid = (lo + hi) >> 1;
            if (batch[mid] < g) lo = mid + 1; else hi = mid;
        }
        start[g] = lo;
        return;
    }
    // ---- block 0: weight chain ----
    __shared__ float sA[OUT_DIM * PADK];
    __shared__ float sB[OUT_DIM * PADK];
    float* cur = sA;
    float* nxt = sB;

    // cur <- fcw^T  (fcw is [128 x 10] row-major)
    for (int idx = t; idx < F_IN * OUT_DIM; idx += 1024) {
        int k = idx / OUT_DIM, c = idx - k * OUT_DIM;
        cur[c * PADK + k] = fcw[idx];
    }
    __syncthreads();
    if (t < OUT_DIM) {                   // r3 = b3^T fcw
        float acc = 0.f;
        const float4* Bv = (const float4*)b3;
        for (int k4 = 0; k4 < F_IN / 4; ++k4) {
            float4 w = Bv[k4];
            float4 b = *(const float4*)&cur[t * PADK + 4 * k4];
            acc += w.x * b.x + w.y * b.y + w.z * b.z + w.w * b.w;
        }
        r3[t] = acc;
    }

    const int r = t >> 2, q = t & 3;
    auto stage = [&](const float* __restrict__ W, const float* __restrict__ bias,
                     float* __restrict__ biasOut, int M, int K, bool toGlobal) {
        const bool isBias = (r == M) && (bias != nullptr);
        const bool active = (r < M) || isBias;
        float acc[OUT_DIM];
        #pragma unroll
        for (int c = 0; c < OUT_DIM; ++c) acc[c] = 0.f;
        if (active) {
            const float* Arow = isBias ? bias : (W + r * K);
            const float4* Wv = (const float4*)Arow;
            const int nit = K >> 4;          // 16 floats per iteration (4 quads)
            #pragma unroll 2
            for (int it = 0; it < nit; ++it) {
                float4 w = Wv[it * 4 + q];
                #pragma unroll
                for (int c = 0; c < OUT_DIM; ++c) {
                    float4 b = *(const float4*)&cur[c * PADK + it * 16 + q * 4];
                    acc[c] += w.x * b.x + w.y * b.y + w.z * b.z + w.w * b.w;
                }
            }
        }
        #pragma unroll
        for (int c = 0; c < OUT_DIM; ++c) {
            acc[c] += __shfl_xor(acc[c], 1);
            acc[c] += __shfl_xor(acc[c], 2);
        }
        if (active && q == 0) {
            if (isBias) {
                #pragma unroll
                for (int c = 0; c < OUT_DIM; ++c) biasOut[c] = acc[c];
            } else if (toGlobal) {
                #pragma unroll
                for (int c = 0; c < OUT_DIM; ++c) Fmt[c * FSTRIDE + r] = acc[c];
            } else {
                #pragma unroll
                for (int c = 0; c < OUT_DIM; ++c) nxt[c * PADK + r] = acc[c];
            }
        }
        __syncthreads();
        float* tmp = cur; cur = nxt; nxt = tmp;
    };

    stage(W3, nullptr, nullptr, HID, F_IN, false);   // T3t = (W3@fcw)^T
    stage(W2, b2, r2, HID, HID, false);              // T2t, r2 = b2@T3
    stage(W1, b1, r1, HID, HID, false);              // T1t, r1 = b1@T2
    stage(W0, b0, r0, F_IN, HID, true);              // Fmt,  r0 = b0@T1
}

// ---- kernel 2: ELL fill XCD-partitioned (blocks < FB) | Y0 = [X@F | ones] (blocks >= FB) ----
// Fill: range r = blockIdx&7 -> nodes [r*6250,(r+1)*6250). Blocks of one residue class land
// on one XCD (round-robin dispatch): ELL rows + deg counters stay in one L2.
// The X@F part streams 25.6 MB of X — co-scheduled with the latency-bound fill (max not sum).
__global__ void k_fill_xf(const int* __restrict__ src, const int* __restrict__ dst,
                          int* __restrict__ deg, int* __restrict__ ell,
                          const float* __restrict__ X, const float* __restrict__ Fmt,
                          float* __restrict__ Y0) {
    const int t = threadIdx.x;
    if (blockIdx.x < FB) {               // ---- ELL fill ----
        const int rb    = blockIdx.x;
        const int range = rb & (NRANGE - 1);
        const int sub   = rb >> 3;                    // 0..FILLB-1
        const int lo    = range * RNODES;
        const int4* d4 = (const int4*)dst;
        const int4* s4 = (const int4*)src;
        for (int pk = sub * 256 + t; pk < NPACK; pk += FILLB * 256) {
            const int4 dv = d4[pk];
            const int4 sv = s4[pk];
            #pragma unroll
            for (int j = 0; j < 4; ++j) {
                const int d = (&dv.x)[j];
                if ((unsigned)(d - lo) < (unsigned)RNODES) {
                    int p = atomicAdd(&deg[d], 1);
                    if (p < MAXDEG) ell[d * MAXDEG + p] = (&sv.x)[j];
                }
            }
        }
        return;
    }
    // ---- X@F part ----
    __shared__ float sX[XF_ROWS][132];   // +4 pad: float4-aligned, conflict-breaking
    __shared__ float sFt[OUT_DIM * FSTRIDE];
    const int base = (blockIdx.x - FB) * XF_ROWS;
    for (int idx = t; idx < XF_ROWS * F_IN; idx += 256) {
        int rr = idx >> 7, kk = idx & 127;
        int gr = base + rr;
        sX[rr][kk] = (gr < N_NODES) ? X[(size_t)gr * F_IN + kk] : 0.f;
    }
    for (int idx = t; idx < OUT_DIM * FSTRIDE; idx += 256) sFt[idx] = Fmt[idx];
    __syncthreads();
    const int r = t >> 4, c = t & 15;
    float a0 = 0.f, a1 = 0.f;
    if (c < OUT_DIM) {
        for (int k = 0; k < F_IN; k += 4) {
            const float4 x0 = *(const float4*)&sX[r][k];
            const float4 x1 = *(const float4*)&sX[r + 16][k];
            const float4 f  = *(const float4*)&sFt[c * FSTRIDE + k];
            a0 += x0.x * f.x + x0.y * f.y + x0.z * f.z + x0.w * f.w;
            a1 += x1.x * f.x + x1.y * f.y + x1.z * f.z + x1.w * f.w;
        }
    }
    const float pad = (c == 10) ? 1.0f : 0.0f;   // col 10 carries the ones vector
    const float v0 = (c < OUT_DIM) ? a0 : pad;
    const float v1 = (c < OUT_DIM) ? a1 : pad;
    const int g0 = base + r, g1 = base + r + 16;
    if (g0 < N_NODES) Y0[(size_t)g0 * PC + c] = v0;
    if (g1 < N_NODES) Y0[(size_t)g1 * PC + c] = v1;
}

// ---------------- propagation: one wave per node; rsqrt computed inline from deg ----------------
__global__ void k_prop16(const float* __restrict__ in, const int* __restrict__ deg,
                         const int* __restrict__ ell, float* __restrict__ out) {
    const int gid  = blockIdx.x * blockDim.x + threadIdx.x;
    const int i    = gid >> 6;                 // node == global wave id (grid exact)
    const int lane = threadIdx.x & 63;
    const int esub = lane >> 4, c = lane & 15;
    const int d = deg[i];
    const int dc = (d < MAXDEG) ? d : MAXDEG;
    float acc = 0.f;
    const int base = i * MAXDEG;
    for (int k = esub; k < dc; k += 4) {
        int s = ell[base + k];
        float ds = rsqrtf((float)deg[s] + 2.0f);
        acc += ds * in[(size_t)s * PC + c];
    }
    acc += __shfl_xor(acc, 16);
    acc += __shfl_xor(acc, 32);
    if (lane < 16) {
        float di = rsqrtf((float)d + 2.0f);
        out[(size_t)i * PC + c] = di * (acc + 2.0f * di * in[(size_t)i * PC + c]);
    }
}

// ---------------- pool + bias terms + fc constant + log_softmax ----------------
__global__ void k_pool_final(const float* __restrict__ Y1, const float* __restrict__ Y2,
                             const float* __restrict__ Y3, const float* __restrict__ Y4,
                             const int* __restrict__ start,
                             const float* __restrict__ r0, const float* __restrict__ r1,
                             const float* __restrict__ r2, const float* __restrict__ r3,
                             const float* __restrict__ fcb, float* __restrict__ out) {
    const int g = blockIdx.x, t = threadIdx.x;  // 256 threads
    __shared__ float red[256];
    __shared__ float S_sh[16];
    __shared__ float qsh[3];
    __shared__ float lg[OUT_DIM];
    const int st = start[g], cnt = start[g + 1] - st;
    const int c = t & 15, rr = t >> 4;

    // S[c] = sum over graph rows of Y4[:, c]
    float acc = 0.f;
    for (int r = rr; r < cnt; r += 16) acc += Y4[(size_t)(st + r) * PC + c];
    red[t] = acc; __syncthreads();
    if (t < 128) red[t] += red[t + 128]; __syncthreads();
    if (t < 64)  red[t] += red[t + 64];  __syncthreads();
    if (t < 32)  red[t] += red[t + 32];  __syncthreads();
    if (t < 16)  S_sh[t] = red[t] + red[t + 16];

    // q1 = sum col10 of Y1, q2 of Y2, q3 of Y3
    float a1 = 0.f, a2 = 0.f, a3 = 0.f;
    for (int r = t; r < cnt; r += 256) {
        a1 += Y1[(size_t)(st + r) * PC + 10];
        a2 += Y2[(size_t)(st + r) * PC + 10];
        a3 += Y3[(size_t)(st + r) * PC + 10];
    }
    __syncthreads(); red[t] = a1; __syncthreads();
    for (int o = 128; o > 0; o >>= 1) { if (t < o) red[t] += red[t + o]; __syncthreads(); }
    if (t == 0) qsh[0] = red[0];
    __syncthreads(); red[t] = a2; __syncthreads();
    for (int o = 128; o > 0; o >>= 1) { if (t < o) red[t] += red[t + o]; __syncthreads(); }
    if (t == 0) qsh[1] = red[0];
    __syncthreads(); red[t] = a3; __syncthreads();
    for (int o = 128; o > 0; o >>= 1) { if (t < o) red[t] += red[t + o]; __syncthreads(); }
    if (t == 0) qsh[2] = red[0];
    __syncthreads();

    if (t < OUT_DIM) {
        float n = (float)cnt; if (n < 1.f) n = 1.f;
        // q3 pairs with r0 = b0^T W1W2W3 fcw; q2 with r1; q1 with r2
        lg[t] = (S_sh[t] + qsh[2] * r0[t] + qsh[1] * r1[t] + qsh[0] * r2[t]) / n
                + r3[t] + fcb[t];
    }
    __syncthreads();
    if (t == 0) {
        float m = -1e30f;
        for (int o = 0; o < OUT_DIM; ++o) m = fmaxf(m, lg[o]);
        float ss = 0.f;
        for (int o = 0; o < OUT_DIM; ++o) ss += expf(lg[o] - m);
        float ls = logf(ss) + m;
        for (int o = 0; o < OUT_DIM; ++o) out[g * OUT_DIM + o] = lg[o] - ls;
    }
}

extern "C" void kernel_launch(void* const* d_in, const int* in_sizes, int n_in,
                              void* d_out, int out_size, void* d_ws, size_t ws_size,
                              hipStream_t stream) {
    const float* x     = (const float*)d_in[0];
    const int*   ei    = (const int*)d_in[1];
    const int*   src   = ei;
    const int*   dstp  = ei + N_EDGES;
    const int*   batch = (const int*)d_in[2];
    const float* W0 = (const float*)d_in[3];
    const float* b0 = (const float*)d_in[4];
    const float* W1 = (const float*)d_in[5];
    const float* b1 = (const float*)d_in[6];
    const float* W2 = (const float*)d_in[7];
    const float* b2 = (const float*)d_in[8];
    const float* W3 = (const float*)d_in[9];
    const float* b3 = (const float*)d_in[10];
    const float* fcw = (const float*)d_in[11];
    const float* fcb = (const float*)d_in[12];
    float* out = (float*)d_out;

    char* p = (char*)d_ws;
    auto alloc = [&](size_t bytes) -> void* {
        void* r = (void*)p;
        p += (bytes + 255) & ~(size_t)255;
        return r;
    };
    int*   deg   = (int*)alloc(N_NODES * 4);
    int*   start = (int*)alloc((NG + 1) * 4);
    int*   ell   = (int*)alloc((size_t)N_NODES * MAXDEG * 4);
    float* Fmt   = (float*)alloc(OUT_DIM * FSTRIDE * 4);
    float* r0    = (float*)alloc(OUT_DIM * 4);
    float* r1    = (float*)alloc(OUT_DIM * 4);
    float* r2    = (float*)alloc(OUT_DIM * 4);
    float* r3    = (float*)alloc(OUT_DIM * 4);
    float* Y0    = (float*)alloc((size_t)N_NODES * PC * 4);
    float* Y1    = (float*)alloc((size_t)N_NODES * PC * 4);
    float* Y2    = (float*)alloc((size_t)N_NODES * PC * 4);
    float* Y3    = (float*)alloc((size_t)N_NODES * PC * 4);
    float* Y4    = (float*)alloc((size_t)N_NODES * PC * 4);

    const int TB = 256;
    // kernel 1: weight chain (quarter-row, 16 waves) + starts + zero deg
    k_init<<<ZERO_BLOCKS + 2, 1024, 0, stream>>>(W0, b0, W1, b1, W2, b2, W3, b3,
                                                 fcw, batch, Fmt, r0, r1, r2, r3,
                                                 start, deg);
    // kernel 2: XCD-partitioned ELL fill + X@F (independent, co-scheduled)
    k_fill_xf<<<FB + XF_BLOCKS, TB, 0, stream>>>(src, dstp, deg, ell, x, Fmt, Y0);

    // 4 propagations of the 16-col matrix (one wave per node, rsqrt inline)
    const int PROP_BLOCKS = N_NODES * 64 / TB;   // 12500
    k_prop16<<<PROP_BLOCKS, TB, 0, stream>>>(Y0, deg, ell, Y1);
    k_prop16<<<PROP_BLOCKS, TB, 0, stream>>>(Y1, deg, ell, Y2);
    k_prop16<<<PROP_BLOCKS, TB, 0, stream>>>(Y2, deg, ell, Y3);
    k_prop16<<<PROP_BLOCKS, TB, 0, stream>>>(Y3, deg, ell, Y4);

    // pool + bias + fc + log_softmax
    k_pool_final<<<NG, TB, 0, stream>>>(Y1, Y2, Y3, Y4, start, r0, r1, r2, r3, fcb, out);
}

// Round 11
// 238.877 us; speedup vs baseline: 1.1076x; 1.0124x over previous
//
#include <hip/hip_runtime.h>

#define N_NODES 50000
#define N_EDGES 500000
#define F_IN    128
#define HID     160
#define NG      50
#define OUT_DIM 10
#define PC      16          // padded column count: 10 logits + col10 = ones-carrier
#define MAXDEG  48          // Poisson(10) max over 50k nodes ~ 30; 48 is beyond-safe
#define PADK    164         // transposed stage-buffer stride (>=160, %4==0)
#define FSTRIDE 132         // Fmt row stride (>=128, %4==0)

#define NRANGE  8           // one dst-range per XCD
#define RNODES  (N_NODES / NRANGE)      // 6250
#define FILLB   128         // fill blocks per range
#define FB      (NRANGE * FILLB)        // 1024 fill blocks
#define NPACK   (N_EDGES / 4)           // 125000 int4 packs

#define XF_ROWS   32
#define XF_BLOCKS ((N_NODES + XF_ROWS - 1) / XF_ROWS)    // 1563
#define ZERO_BLOCKS ((N_NODES + 1023) / 1024)            // 49

// ---- kernel 1: weight chain (block 0) | starts (block 1) | zero deg (blocks 2+) ----
// Quarter-row threads: thread (r=t>>2, q=t&3) loads W[r, quarter q] as 10 float4s
// (row-quad reads 64 B contiguous); quad-reduce via shfl_xor(1,2).
__global__ __launch_bounds__(1024)
void k_init(const float* __restrict__ W0, const float* __restrict__ b0,
            const float* __restrict__ W1, const float* __restrict__ b1,
            const float* __restrict__ W2, const float* __restrict__ b2,
            const float* __restrict__ W3, const float* __restrict__ b3,
            const float* __restrict__ fcw, const int* __restrict__ batch,
            float* __restrict__ Fmt, float* __restrict__ r0,
            float* __restrict__ r1, float* __restrict__ r2,
            float* __restrict__ r3, int* __restrict__ start,
            int* __restrict__ deg) {
    const int t = threadIdx.x;
    if (blockIdx.x >= 2) {               // ---- zero deg ----
        int i = (blockIdx.x - 2) * 1024 + t;
        if (i < N_NODES) deg[i] = 0;
        return;
    }
    if (blockIdx.x == 1) {               // ---- per-graph starts (batch sorted) ----
        int g = t;
        if (g > NG) return;
        int lo = 0, hi = N_NODES;
        while (lo < hi) {
            int mid = (lo + hi) >> 1;
            if (batch[mid] < g) lo = mid + 1; else hi = mid;
        }
        start[g] = lo;
        return;
    }
    // ---- block 0: weight chain ----
    __shared__ float sA[OUT_DIM * PADK];
    __shared__ float sB[OUT_DIM * PADK];
    float* cur = sA;
    float* nxt = sB;

    for (int idx = t; idx < F_IN * OUT_DIM; idx += 1024) {
        int k = idx / OUT_DIM, c = idx - k * OUT_DIM;
        cur[c * PADK + k] = fcw[idx];
    }
    __syncthreads();
    if (t < OUT_DIM) {                   // r3 = b3^T fcw
        float acc = 0.f;
        const float4* Bv = (const float4*)b3;
        for (int k4 = 0; k4 < F_IN / 4; ++k4) {
            float4 w = Bv[k4];
            float4 b = *(const float4*)&cur[t * PADK + 4 * k4];
            acc += w.x * b.x + w.y * b.y + w.z * b.z + w.w * b.w;
        }
        r3[t] = acc;
    }

    const int r = t >> 2, q = t & 3;
    auto stage = [&](const float* __restrict__ W, const float* __restrict__ bias,
                     float* __restrict__ biasOut, int M, int K, bool toGlobal) {
        const bool isBias = (r == M) && (bias != nullptr);
        const bool active = (r < M) || isBias;
        float acc[OUT_DIM];
        #pragma unroll
        for (int c = 0; c < OUT_DIM; ++c) acc[c] = 0.f;
        if (active) {
            const float* Arow = isBias ? bias : (W + r * K);
            const float4* Wv = (const float4*)Arow;
            const int nit = K >> 4;
            #pragma unroll 2
            for (int it = 0; it < nit; ++it) {
                float4 w = Wv[it * 4 + q];
                #pragma unroll
                for (int c = 0; c < OUT_DIM; ++c) {
                    float4 b = *(const float4*)&cur[c * PADK + it * 16 + q * 4];
                    acc[c] += w.x * b.x + w.y * b.y + w.z * b.z + w.w * b.w;
                }
            }
        }
        #pragma unroll
        for (int c = 0; c < OUT_DIM; ++c) {
            acc[c] += __shfl_xor(acc[c], 1);
            acc[c] += __shfl_xor(acc[c], 2);
        }
        if (active && q == 0) {
            if (isBias) {
                #pragma unroll
                for (int c = 0; c < OUT_DIM; ++c) biasOut[c] = acc[c];
            } else if (toGlobal) {
                #pragma unroll
                for (int c = 0; c < OUT_DIM; ++c) Fmt[c * FSTRIDE + r] = acc[c];
            } else {
                #pragma unroll
                for (int c = 0; c < OUT_DIM; ++c) nxt[c * PADK + r] = acc[c];
            }
        }
        __syncthreads();
        float* tmp = cur; cur = nxt; nxt = tmp;
    };

    stage(W3, nullptr, nullptr, HID, F_IN, false);   // T3t = (W3@fcw)^T
    stage(W2, b2, r2, HID, HID, false);              // T2t, r2 = b2@T3
    stage(W1, b1, r1, HID, HID, false);              // T1t, r1 = b1@T2
    stage(W0, b0, r0, F_IN, HID, true);              // Fmt,  r0 = b0@T1
}

// ---- kernel 2: ELL fill XCD-partitioned (blocks < FB) | Y0 = [X@F | ones] (blocks >= FB) ----
// ELL entries are ushort (node id < 65536): halves scatter write-back + prop ELL stream.
__global__ void k_fill_xf(const int* __restrict__ src, const int* __restrict__ dst,
                          int* __restrict__ deg, unsigned short* __restrict__ ell,
                          const float* __restrict__ X, const float* __restrict__ Fmt,
                          float* __restrict__ Y0) {
    const int t = threadIdx.x;
    if (blockIdx.x < FB) {               // ---- ELL fill ----
        const int rb    = blockIdx.x;
        const int range = rb & (NRANGE - 1);
        const int sub   = rb >> 3;
        const int lo    = range * RNODES;
        const int4* d4 = (const int4*)dst;
        const int4* s4 = (const int4*)src;
        for (int pk = sub * 256 + t; pk < NPACK; pk += FILLB * 256) {
            const int4 dv = d4[pk];
            const int4 sv = s4[pk];
            #pragma unroll
            for (int j = 0; j < 4; ++j) {
                const int d = (&dv.x)[j];
                if ((unsigned)(d - lo) < (unsigned)RNODES) {
                    int p = atomicAdd(&deg[d], 1);
                    if (p < MAXDEG) ell[d * MAXDEG + p] = (unsigned short)(&sv.x)[j];
                }
            }
        }
        return;
    }
    // ---- X@F part (Y0 unscaled; first prop applies D^{-1/2} per edge) ----
    __shared__ float sX[XF_ROWS][132];
    __shared__ float sFt[OUT_DIM * FSTRIDE];
    const int base = (blockIdx.x - FB) * XF_ROWS;
    for (int idx = t; idx < XF_ROWS * F_IN; idx += 256) {
        int rr = idx >> 7, kk = idx & 127;
        int gr = base + rr;
        sX[rr][kk] = (gr < N_NODES) ? X[(size_t)gr * F_IN + kk] : 0.f;
    }
    for (int idx = t; idx < OUT_DIM * FSTRIDE; idx += 256) sFt[idx] = Fmt[idx];
    __syncthreads();
    const int r = t >> 4, c = t & 15;
    float a0 = 0.f, a1 = 0.f;
    if (c < OUT_DIM) {
        for (int k = 0; k < F_IN; k += 4) {
            const float4 x0 = *(const float4*)&sX[r][k];
            const float4 x1 = *(const float4*)&sX[r + 16][k];
            const float4 f  = *(const float4*)&sFt[c * FSTRIDE + k];
            a0 += x0.x * f.x + x0.y * f.y + x0.z * f.z + x0.w * f.w;
            a1 += x1.x * f.x + x1.y * f.y + x1.z * f.z + x1.w * f.w;
        }
    }
    const float pad = (c == 10) ? 1.0f : 0.0f;   // col 10 carries the ones vector
    const float v0 = (c < OUT_DIM) ? a0 : pad;
    const float v1 = (c < OUT_DIM) ? a1 : pad;
    const int g0 = base + r, g1 = base + r + 16;
    if (g0 < N_NODES) Y0[(size_t)g0 * PC + c] = v0;
    if (g1 < N_NODES) Y0[(size_t)g1 * PC + c] = v1;
}

// ---- propagation in Z-space (Z = D^{-1/2} Y): one wave per node ----
// MODE 0 (first): in = Y0 unscaled -> Z1_i = (sum_s dinv_s*Y0_s + 2*dinv_i*Y0_i)/(deg_i+2)
// MODE 1 (mid):   Z_{l+1,i} = (sum_s Z_s + 2*Z_i)/(deg_i+2)     [no per-edge deg gather!]
// MODE 2 (last):  Y4_i = (sum_s Z_s + 2*Z_i)*rsqrt(deg_i+2)
template<int MODE>
__global__ void k_prop16(const float* __restrict__ in, const int* __restrict__ deg,
                         const unsigned short* __restrict__ ell, float* __restrict__ out) {
    const int gid  = blockIdx.x * blockDim.x + threadIdx.x;
    const int i    = gid >> 6;                 // node == global wave id (grid exact)
    const int lane = threadIdx.x & 63;
    const int esub = lane >> 4, c = lane & 15;
    const int d = deg[i];
    const int dc = (d < MAXDEG) ? d : MAXDEG;
    float acc = 0.f;
    const int base = i * MAXDEG;
    for (int k = esub; k < dc; k += 4) {
        int s = ell[base + k];
        if (MODE == 0) acc += rsqrtf((float)deg[s] + 2.0f) * in[(size_t)s * PC + c];
        else           acc += in[(size_t)s * PC + c];
    }
    acc += __shfl_xor(acc, 16);
    acc += __shfl_xor(acc, 32);
    if (lane < 16) {
        const float self = in[(size_t)i * PC + c];
        const float dp2 = (float)d + 2.0f;
        float o;
        if (MODE == 0)      o = (acc + 2.0f * rsqrtf(dp2) * self) / dp2;
        else if (MODE == 1) o = (acc + 2.0f * self) / dp2;
        else                o = (acc + 2.0f * self) * rsqrtf(dp2);
        out[(size_t)i * PC + c] = o;
    }
}

// ---- pool + bias terms + fc constant + log_softmax ----
// S sums Y4 (true scale). q-sums read col 10 of Z1..Z3, rescaled by sqrt(deg_i+2).
__global__ void k_pool_final(const float* __restrict__ Z1, const float* __restrict__ Z2,
                             const float* __restrict__ Z3, const float* __restrict__ Y4,
                             const int* __restrict__ start, const int* __restrict__ deg,
                             const float* __restrict__ r0, const float* __restrict__ r1,
                             const float* __restrict__ r2, const float* __restrict__ r3,
                             const float* __restrict__ fcb, float* __restrict__ out) {
    const int g = blockIdx.x, t = threadIdx.x;  // 256 threads
    __shared__ float red[256];
    __shared__ float S_sh[16];
    __shared__ float qsh[3];
    __shared__ float lg[OUT_DIM];
    const int st = start[g], cnt = start[g + 1] - st;
    const int c = t & 15, rr = t >> 4;

    // S[c] = sum over graph rows of Y4[:, c]
    float acc = 0.f;
    for (int r = rr; r < cnt; r += 16) acc += Y4[(size_t)(st + r) * PC + c];
    red[t] = acc; __syncthreads();
    if (t < 128) red[t] += red[t + 128]; __syncthreads();
    if (t < 64)  red[t] += red[t + 64];  __syncthreads();
    if (t < 32)  red[t] += red[t + 32];  __syncthreads();
    if (t < 16)  S_sh[t] = red[t] + red[t + 16];

    // q_k = sum over graph of sqrt(deg+2) * Zk[:,10]
    float a1 = 0.f, a2 = 0.f, a3 = 0.f;
    for (int r = t; r < cnt; r += 256) {
        const float sq = sqrtf((float)deg[st + r] + 2.0f);
        a1 += sq * Z1[(size_t)(st + r) * PC + 10];
        a2 += sq * Z2[(size_t)(st + r) * PC + 10];
        a3 += sq * Z3[(size_t)(st + r) * PC + 10];
    }
    __syncthreads(); red[t] = a1; __syncthreads();
    for (int o = 128; o > 0; o >>= 1) { if (t < o) red[t] += red[t + o]; __syncthreads(); }
    if (t == 0) qsh[0] = red[0];
    __syncthreads(); red[t] = a2; __syncthreads();
    for (int o = 128; o > 0; o >>= 1) { if (t < o) red[t] += red[t + o]; __syncthreads(); }
    if (t == 0) qsh[1] = red[0];
    __syncthreads(); red[t] = a3; __syncthreads();
    for (int o = 128; o > 0; o >>= 1) { if (t < o) red[t] += red[t + o]; __syncthreads(); }
    if (t == 0) qsh[2] = red[0];
    __syncthreads();

    if (t < OUT_DIM) {
        float n = (float)cnt; if (n < 1.f) n = 1.f;
        // q3 pairs with r0 = b0^T W1W2W3 fcw; q2 with r1; q1 with r2
        lg[t] = (S_sh[t] + qsh[2] * r0[t] + qsh[1] * r1[t] + qsh[0] * r2[t]) / n
                + r3[t] + fcb[t];
    }
    __syncthreads();
    if (t == 0) {
        float m = -1e30f;
        for (int o = 0; o < OUT_DIM; ++o) m = fmaxf(m, lg[o]);
        float ss = 0.f;
        for (int o = 0; o < OUT_DIM; ++o) ss += expf(lg[o] - m);
        float ls = logf(ss) + m;
        for (int o = 0; o < OUT_DIM; ++o) out[g * OUT_DIM + o] = lg[o] - ls;
    }
}

extern "C" void kernel_launch(void* const* d_in, const int* in_sizes, int n_in,
                              void* d_out, int out_size, void* d_ws, size_t ws_size,
                              hipStream_t stream) {
    const float* x     = (const float*)d_in[0];
    const int*   ei    = (const int*)d_in[1];
    const int*   src   = ei;
    const int*   dstp  = ei + N_EDGES;
    const int*   batch = (const int*)d_in[2];
    const float* W0 = (const float*)d_in[3];
    const float* b0 = (const float*)d_in[4];
    const float* W1 = (const float*)d_in[5];
    const float* b1 = (const float*)d_in[6];
    const float* W2 = (const float*)d_in[7];
    const float* b2 = (const float*)d_in[8];
    const float* W3 = (const float*)d_in[9];
    const float* b3 = (const float*)d_in[10];
    const float* fcw = (const float*)d_in[11];
    const float* fcb = (const float*)d_in[12];
    float* out = (float*)d_out;

    char* p = (char*)d_ws;
    auto alloc = [&](size_t bytes) -> void* {
        void* r = (void*)p;
        p += (bytes + 255) & ~(size_t)255;
        return r;
    };
    int*            deg   = (int*)alloc(N_NODES * 4);
    int*            start = (int*)alloc((NG + 1) * 4);
    unsigned short* ell   = (unsigned short*)alloc((size_t)N_NODES * MAXDEG * 2);
    float* Fmt   = (float*)alloc(OUT_DIM * FSTRIDE * 4);
    float* r0    = (float*)alloc(OUT_DIM * 4);
    float* r1    = (float*)alloc(OUT_DIM * 4);
    float* r2    = (float*)alloc(OUT_DIM * 4);
    float* r3    = (float*)alloc(OUT_DIM * 4);
    float* Y0    = (float*)alloc((size_t)N_NODES * PC * 4);
    float* Z1    = (float*)alloc((size_t)N_NODES * PC * 4);
    float* Z2    = (float*)alloc((size_t)N_NODES * PC * 4);
    float* Z3    = (float*)alloc((size_t)N_NODES * PC * 4);
    float* Y4    = (float*)alloc((size_t)N_NODES * PC * 4);

    const int TB = 256;
    // kernel 1: weight chain + starts + zero deg
    k_init<<<ZERO_BLOCKS + 2, 1024, 0, stream>>>(W0, b0, W1, b1, W2, b2, W3, b3,
                                                 fcw, batch, Fmt, r0, r1, r2, r3,
                                                 start, deg);
    // kernel 2: XCD-partitioned ELL fill (ushort) + X@F
    k_fill_xf<<<FB + XF_BLOCKS, TB, 0, stream>>>(src, dstp, deg, ell, x, Fmt, Y0);

    // 4 propagations (Z-space: only the first pays per-edge deg gathers)
    const int PROP_BLOCKS = N_NODES * 64 / TB;   // 12500
    k_prop16<0><<<PROP_BLOCKS, TB, 0, stream>>>(Y0, deg, ell, Z1);
    k_prop16<1><<<PROP_BLOCKS, TB, 0, stream>>>(Z1, deg, ell, Z2);
    k_prop16<1><<<PROP_BLOCKS, TB, 0, stream>>>(Z2, deg, ell, Z3);
    k_prop16<2><<<PROP_BLOCKS, TB, 0, stream>>>(Z3, deg, ell, Y4);

    // pool + bias + fc + log_softmax
    k_pool_final<<<NG, TB, 0, stream>>>(Z1, Z2, Z3, Y4, start, deg,
                                        r0, r1, r2, r3, fcb, out);
}